// Round 6
// baseline (133.625 us; speedup 1.0000x reference)
//
#include <hip/hip_runtime.h>
#include <math.h>

#define BB 4
#define CC 256
#define LL 4096
#define DD 32   // q/k channels
#define LOG2E 1.44269504088896f

typedef __attribute__((ext_vector_type(8))) short short8;   // 8 bf16 (4 VGPRs)
typedef __attribute__((ext_vector_type(4))) short short4v;
typedef __attribute__((ext_vector_type(4))) float f32x4;
typedef __attribute__((ext_vector_type(16))) float f32x16;  // 32x32 accumulator
typedef __attribute__((ext_vector_type(4))) unsigned int uint4v;
typedef __attribute__((ext_vector_type(2))) unsigned int uint2v;

// raw workgroup barrier: waits LDS ops only — global prefetches stay in flight
#define BARRIER() asm volatile("s_waitcnt lgkmcnt(0)\n\ts_barrier" ::: "memory")

__device__ inline unsigned short f2bf(float f) {
  union { float f; unsigned u; } v; v.f = f;
  unsigned r = v.u + 0x7fffu + ((v.u >> 16) & 1u);  // RNE
  return (unsigned short)(r >> 16);
}

__device__ inline float fast_exp2(float x) {
#if __has_builtin(__builtin_amdgcn_exp2f)
  return __builtin_amdgcn_exp2f(x);
#else
  return exp2f(x);
#endif
}

// ---------------- kernel 0: W -> bf16 MFMA-fragment-linear layout ----------------
// wf[ot(20)][ks(8)][lane(64)][8]; Wq rows pre-scaled by log2(e).
__global__ __launch_bounds__(256) void wprep_kernel(
    const float* __restrict__ Wq, const float* __restrict__ Wk, const float* __restrict__ Wv,
    unsigned short* __restrict__ wf)
{
  const int t = threadIdx.x;
  const int ot = blockIdx.x >> 1;           // 0..19
  const int rep = blockIdx.x & 1;
  const int lane = t & 63, cl = lane & 15, q4 = lane >> 4;
  const int ks = (t >> 6) + 4 * rep;        // 0..7
  const int o = ot * 16 + cl;
  const int c = ks * 32 + q4 * 8;
  const float* src = (o < 32) ? (Wq + o * CC) : (o < 64) ? (Wk + (o - 32) * CC)
                                              : (Wv + (o - 64) * CC);
  const float sc = (o < 32) ? LOG2E : 1.0f;
  unsigned short p[8];
  #pragma unroll
  for (int j = 0; j < 8; ++j) p[j] = f2bf(src[c + j] * sc);
  uint4v u;
  u.x = (unsigned)p[0] | ((unsigned)p[1] << 16);
  u.y = (unsigned)p[2] | ((unsigned)p[3] << 16);
  u.z = (unsigned)p[4] | ((unsigned)p[5] << 16);
  u.w = (unsigned)p[6] | ((unsigned)p[7] << 16);
  *(uint4v*)(wf + ((size_t)(ot * 8 + ks) * 64 + lane) * 8) = u;
}

// ---------------- kernel 1: fused transpose + QKV projection ----------------
// grid 512 = (b, it 32-i tile) XCD-affine; 512 thr = 8 waves (wi 16-i, wo 5-ot).
// R12: epilogue emits 32x32-MFMA fragment-linear qF/kF/vF (no sigma permutation).
__global__ __launch_bounds__(512, 4) void qkv_kernel(
    const float* __restrict__ x, const unsigned short* __restrict__ wf,
    const float* __restrict__ bq, const float* __restrict__ bk, const float* __restrict__ bv,
    unsigned short* __restrict__ qF, unsigned short* __restrict__ kF,
    unsigned short* __restrict__ vF)
{
  __shared__ union {
    float xl[32 * 261];                                   // [i][c] odd stride
    struct {
      unsigned short qk[32 * 72];                         // [i][o 0..63]
      __align__(16) unsigned short v[256 * 40];           // [ch][key 0..31] pad-40
    } ep;
  } sm;

  const int t = threadIdx.x;
  const int lane = t & 63, cl = lane & 15, q4 = lane >> 4;
  const int blk = blockIdx.x;
  const int b  = (blk & 7) >> 1;                          // XCD-batch affinity
  const int it = ((blk >> 3) << 1) + (blk & 1);           // 0..127
  const int i0 = it * 32;

  // ---- stage x: coalesced 128B rows -> LDS transposed ----
  {
    const int ln8 = t & 7;
    #pragma unroll
    for (int p = 0; p < 4; ++p) {
      const int c = (t >> 3) + 64 * p;
      const f32x4 v = *(const f32x4*)(x + ((size_t)(b * CC + c)) * LL + i0 + ln8 * 4);
      #pragma unroll
      for (int k = 0; k < 4; ++k) sm.xl[(ln8 * 4 + k) * 261 + c] = v[k];
    }
  }
  __syncthreads();

  // ---- GEMM: wave (wi,wo): 80 o-rows x 16 i x 256 c ----
  const int wi = (t >> 6) & 1, wo = t >> 7;
  const f32x4 zero = {0.f, 0.f, 0.f, 0.f};
  f32x4 acc[5];
  #pragma unroll
  for (int u = 0; u < 5; ++u) acc[u] = zero;

  for (int ks = 0; ks < 8; ++ks) {
    unsigned short p[8];
    #pragma unroll
    for (int j = 0; j < 8; ++j)
      p[j] = f2bf(sm.xl[(16 * wi + cl) * 261 + ks * 32 + q4 * 8 + j]);
    union { short8 s; uint4v u; } bfr;
    bfr.u.x = (unsigned)p[0] | ((unsigned)p[1] << 16);
    bfr.u.y = (unsigned)p[2] | ((unsigned)p[3] << 16);
    bfr.u.z = (unsigned)p[4] | ((unsigned)p[5] << 16);
    bfr.u.w = (unsigned)p[6] | ((unsigned)p[7] << 16);
    #pragma unroll
    for (int u = 0; u < 5; ++u) {
      const short8 a = *(const short8*)(wf + ((size_t)((wo * 5 + u) * 8 + ks) * 64 + lane) * 8);
      acc[u] = __builtin_amdgcn_mfma_f32_16x16x32_bf16(a, bfr.s, acc[u], 0, 0, 0);
    }
  }
  __syncthreads();   // xl dead; alias as ep

  // ---- stage outputs ----
  #pragma unroll
  for (int u = 0; u < 5; ++u) {
    const int g = wo * 5 + u;
    if (g < 4) {     // q (g<2) / k
      short4v pk;
      #pragma unroll
      for (int r = 0; r < 4; ++r) {
        const int o = 16 * g + 4 * q4 + r;
        const float v = acc[u][r] + ((o < 32) ? bq[o] * LOG2E : bk[o - 32]);
        pk[r] = (short)f2bf(v);
      }
      *(short4v*)&sm.ep.qk[(16 * wi + cl) * 72 + 16 * g + 4 * q4] = pk;
    } else {
      #pragma unroll
      for (int r = 0; r < 4; ++r) {
        const int ch = 16 * (g - 4) + 4 * q4 + r;
        sm.ep.v[ch * 40 + 16 * wi + cl] = f2bf(acc[u][r] + bv[ch]);
      }
    }
  }
  __syncthreads();

  // ---- emit 32x32-fragment-linear outputs ----
  // qF/kF: A/B-frags for this block's 32-row tile, 2 ch-chunks of 16.
  // lane l: row = l&31, k = chunk*16 + 8*(l>>5) + j  (j contiguous in memory)
  if (t < 256) {
    const int which = t >> 7;              // 0: qF, 1: kF
    const int c = (t >> 6) & 1;
    const int l = t & 63, hi2 = l >> 5, ql2 = l & 31;
    const uint4v d = *(const uint4v*)&sm.ep.qk[ql2 * 72 + which * 32 + c * 16 + hi2 * 8];
    unsigned short* dstf = which ? kF : qF;
    *(uint4v*)(dstf + (((size_t)(b * 128 + it) * 2 + c) * 64 + l) * 8) = d;
  }
  // vF: A-frags (ch-32-tile m, key-16-group kg = 2*it+g):
  // lane l: ch = 32m + (l&31), key = kg*16 + 8*(l>>5) + j
  #pragma unroll
  for (int rep = 0; rep < 2; ++rep) {
    const int slot = t + 512 * rep;
    const int fl = slot >> 6, l = slot & 63;
    const int g = fl >> 3, m = fl & 7;
    const int hi2 = l >> 5, cl2 = l & 31;
    const uint4v d = *(const uint4v*)&sm.ep.v[(32 * m + cl2) * 40 + g * 16 + hi2 * 8];
    *(uint4v*)(vF + (((size_t)(b * 256 + 2 * it + g) * 8 + m) * 64 + l) * 8) = d;
  }
}

// ---------------- kernel 2: flash attention, 32x32 MFMA, producer/consumer ----------------
// R12: all MFMAs switched to 32x32x16 (15.8 cyc / 32k FLOP vs 19.4 / 16k: 2.45x
// matrix-pipe efficiency; per-SIMD matrix demand 2790 -> 1140 cyc/window).
// 768 thr = 8 producers (1 key-32-tile each: 4 MFMA + 32 exp + permlane-packed P)
// + 4 consumers (64 ch each over all keys: 16 steps x {2 ds_read_b128, 4 MFMA}).
// P granule layout [kk][qt][c]: lane l: addr = (l>>5)*512B + (l&31)*16B -> all
// P reads/writes are contiguous-1KB b128, conflict-free.
__global__ __launch_bounds__(768, 3) void attn_kernel(
    const unsigned short* __restrict__ qF, const unsigned short* __restrict__ kF,
    const unsigned short* __restrict__ vF, const float* __restrict__ x,
    const float* __restrict__ gamma_p, float* __restrict__ out)
{
  __shared__ __align__(16) unsigned short P[2 * 8 * 2 * 2 * 512];  // 64 KB ring (2 bufs)
  __shared__ float l_lds[8][2][64];                                // [pw][qt][lane] 4 KB

  const int t = threadIdx.x;
  const int w = t >> 6, lane = t & 63, ql = lane & 31, hi = lane >> 5;
  const int blk = blockIdx.x;
  const int b  = (blk & 7) >> 1;                          // matches qkv affinity
  const int it = ((blk >> 3) << 1) + (blk & 1);           // 0..63
  const int i0 = it * 64;

  if (w < 8) {
    // ================= producer: key-tile kk = pw of each window =================
    const int pw = w;
    short8 qB[2][2];                       // [qt][chunk]
    #pragma unroll
    for (int qt = 0; qt < 2; ++qt)
      #pragma unroll
      for (int c = 0; c < 2; ++c)
        qB[qt][c] = *(const short8*)(qF +
            (((size_t)(b * 128 + it * 2 + qt) * 2 + c) * 64 + lane) * 8);
    short8 kA[2];                          // [chunk], tile ss*8+pw
    #pragma unroll
    for (int c = 0; c < 2; ++c)
      kA[c] = *(const short8*)(kF + (((size_t)(b * 128 + pw) * 2 + c) * 64 + lane) * 8);
    float l_r[2] = {0.f, 0.f};
    const f32x16 z16 = {0.f,0.f,0.f,0.f,0.f,0.f,0.f,0.f,0.f,0.f,0.f,0.f,0.f,0.f,0.f,0.f};

    auto produce = [&](int ss, int buf) {
      f32x16 S[2];
      __builtin_amdgcn_s_setprio(1);
      #pragma unroll
      for (int qt = 0; qt < 2; ++qt)
        S[qt] = __builtin_amdgcn_mfma_f32_32x32x16_bf16(kA[0], qB[qt][0], z16, 0, 0, 0);
      #pragma unroll
      for (int qt = 0; qt < 2; ++qt)
        S[qt] = __builtin_amdgcn_mfma_f32_32x32x16_bf16(kA[1], qB[qt][1], S[qt], 0, 0, 0);
      __builtin_amdgcn_s_setprio(0);
      // prefetch next window's kA (global; stays in flight across barrier)
      const int ntile = ((ss + 1) & 15) * 8 + pw;
      #pragma unroll
      for (int c = 0; c < 2; ++c)
        kA[c] = *(const short8*)(kF + (((size_t)(b * 128 + ntile) * 2 + c) * 64 + lane) * 8);
      // exp + pack: D row = (r&3)+8*(r>>2)+4*hi (key), col = q = l&31
      #pragma unroll
      for (int qt = 0; qt < 2; ++qt) {
        float ex[16];
        #pragma unroll
        for (int r = 0; r < 16; ++r) ex[r] = fast_exp2(S[qt][r]);
        l_r[qt] += ((((ex[0] + ex[1]) + (ex[2] + ex[3])) + ((ex[4] + ex[5]) + (ex[6] + ex[7])))
                 + (((ex[8] + ex[9]) + (ex[10] + ex[11])) + ((ex[12] + ex[13]) + (ex[14] + ex[15]))));
        #pragma unroll
        for (int c = 0; c < 2; ++c) {
          // regs 8c..8c+3 -> keys 16c+4hi+{0..3}; 8c+4..8c+7 -> keys 16c+8+4hi+{0..3}
          unsigned w0, w1, w2, w3;
          asm("v_cvt_pk_bf16_f32 %0, %1, %2" : "=v"(w0) : "v"(ex[8 * c + 0]), "v"(ex[8 * c + 1]));
          asm("v_cvt_pk_bf16_f32 %0, %1, %2" : "=v"(w1) : "v"(ex[8 * c + 2]), "v"(ex[8 * c + 3]));
          asm("v_cvt_pk_bf16_f32 %0, %1, %2" : "=v"(w2) : "v"(ex[8 * c + 4]), "v"(ex[8 * c + 5]));
          asm("v_cvt_pk_bf16_f32 %0, %1, %2" : "=v"(w3) : "v"(ex[8 * c + 6]), "v"(ex[8 * c + 7]));
          // swap hi/lo lane halves so each lane holds one full 16B k-granule
          asm("v_permlane32_swap_b32 %0, %1" : "+v"(w0), "+v"(w2));
          asm("v_permlane32_swap_b32 %0, %1" : "+v"(w1), "+v"(w3));
          uint4v u; u.x = w0; u.y = w1; u.z = w2; u.w = w3;
          *(uint4v*)(&P[(((buf * 8 + pw) * 2 + qt) * 2 + c) * 512 + hi * 256 + ql * 8]) = u;
        }
      }
    };

    produce(0, 0);
    __syncthreads();   // P(0) ready
    for (int i = 0; i < 16; ++i) {
      if (i < 15) produce(i + 1, (i + 1) & 1);
      BARRIER();
    }
    l_lds[pw][0][lane] = l_r[0];
    l_lds[pw][1][lane] = l_r[1];
    BARRIER();
  } else {
    // ================= consumer: ch 64*mq..+63 over ALL keys =================
    const int mq = w - 8;
    const unsigned short* vroot = vF + (size_t)b * (256 * 8 * 512) + lane * 8;
    f32x16 O[2][2];                       // [mi][qt]
    #pragma unroll
    for (int mi = 0; mi < 2; ++mi)
      #pragma unroll
      for (int qt = 0; qt < 2; ++qt) {
        const f32x16 z16 = {0.f,0.f,0.f,0.f,0.f,0.f,0.f,0.f,0.f,0.f,0.f,0.f,0.f,0.f,0.f,0.f};
        O[mi][qt] = z16;
      }
    short8 vA[4][2];                      // 4-slot ring [g&3][mi], ~250 cyc slack
    #pragma unroll
    for (int s = 0; s < 4; ++s)
      #pragma unroll
      for (int mi = 0; mi < 2; ++mi)
        vA[s][mi] = *(const short8*)(vroot + ((size_t)(s * 8 + 2 * mq + mi)) * 512);
    __syncthreads();   // P(0) ready

    short8 pb[3][2];                      // 3-slot ring [s%3][qt]
    for (int i = 0; i < 16; ++i) {
      const int buf = i & 1;
      // preload steps 0,1 (kk=0, c=0/1)
      #pragma unroll
      for (int s = 0; s < 2; ++s)
        #pragma unroll
        for (int qt = 0; qt < 2; ++qt)
          pb[s][qt] = *(const short8*)(&P[((((buf * 8 + 0) * 2 + qt) * 2 + s) * 512)
                                          + hi * 256 + ql * 8]);
      #pragma unroll
      for (int s = 0; s < 16; ++s) {      // step s: kk = s>>1, c = s&1
        if (s < 14) {                     // prefetch pb 2 steps ahead
          const int ns = s + 2, kk = ns >> 1, c = ns & 1;
          #pragma unroll
          for (int qt = 0; qt < 2; ++qt)
            pb[ns % 3][qt] = *(const short8*)(&P[((((buf * 8 + kk) * 2 + qt) * 2 + c) * 512)
                                                 + hi * 256 + ql * 8]);
        }
        __builtin_amdgcn_s_setprio(1);
        #pragma unroll
        for (int mi = 0; mi < 2; ++mi)
          #pragma unroll
          for (int qt = 0; qt < 2; ++qt)
            O[mi][qt] = __builtin_amdgcn_mfma_f32_32x32x16_bf16(vA[s & 3][mi], pb[s % 3][qt],
                                                                O[mi][qt], 0, 0, 0);
        __builtin_amdgcn_s_setprio(0);
        // refill vA slot s&3 with key-group 4 steps ahead (wraps across windows)
        const int kg = (i * 16 + s + 4) & 255;
        #pragma unroll
        for (int mi = 0; mi < 2; ++mi)
          vA[s & 3][mi] = *(const short8*)(vroot + ((size_t)(kg * 8 + 2 * mq + mi)) * 512);
      }
      BARRIER();
    }
    BARRIER();   // l_lds visible

    // ---- epilogue: no cross-wave O combine; normalize + residual ----
    const float gam = gamma_p[0];
    float inv_l[2];
    #pragma unroll
    for (int qt = 0; qt < 2; ++qt) {
      float s = 0.f;
      #pragma unroll
      for (int pw = 0; pw < 8; ++pw)
        s += l_lds[pw][qt][ql] + l_lds[pw][qt][ql + 32];
      inv_l[qt] = 1.0f / s;
    }
    #pragma unroll
    for (int mi = 0; mi < 2; ++mi)
      #pragma unroll
      for (int qt = 0; qt < 2; ++qt)
        #pragma unroll
        for (int r = 0; r < 16; ++r) {
          const int ch = 64 * mq + 32 * mi + (r & 3) + 8 * (r >> 2) + 4 * hi;
          const int ii = i0 + 32 * qt + ql;
          const size_t idx = ((size_t)b * CC + ch) * LL + ii;
          out[idx] = gam * O[mi][qt][r] * inv_l[qt] + x[idx];
        }
  }
}

extern "C" void kernel_launch(void* const* d_in, const int* in_sizes, int n_in,
                              void* d_out, int out_size, void* d_ws, size_t ws_size,
                              hipStream_t stream) {
  const float* x     = (const float*)d_in[0];
  const float* Wq    = (const float*)d_in[1];
  const float* bq    = (const float*)d_in[2];
  const float* Wk    = (const float*)d_in[3];
  const float* bk    = (const float*)d_in[4];
  const float* Wv    = (const float*)d_in[5];
  const float* bv    = (const float*)d_in[6];
  const float* gamma = (const float*)d_in[7];
  float* out = (float*)d_out;

  // ws: qF (1MB) | kF (1MB) | vF (8MB) — all 32x32-fragment-linear bf16
  unsigned short* qF = (unsigned short*)d_ws;
  unsigned short* kF = qF + (size_t)BB * LL * DD;
  unsigned short* vF = kF + (size_t)BB * LL * DD;
  // wf (160KB) lives in d_out; consumed by qkv, then attn overwrites d_out
  unsigned short* wf = (unsigned short*)d_out;

  wprep_kernel<<<40, 256, 0, stream>>>(Wq, Wk, Wv, wf);
  qkv_kernel<<<512, 512, 0, stream>>>(x, wf, bq, bk, bv, qF, kF, vF);
  attn_kernel<<<256, 768, 0, stream>>>(qF, kF, vF, x, gamma, out);
}

// Round 7
// 129.835 us; speedup vs baseline: 1.0292x; 1.0292x over previous
//
#include <hip/hip_runtime.h>
#include <math.h>

#define BB 4
#define CC 256
#define LL 4096
#define DD 32   // q/k channels
#define LOG2E 1.44269504088896f

typedef __attribute__((ext_vector_type(8))) short short8;   // 8 bf16 (4 VGPRs)
typedef __attribute__((ext_vector_type(4))) short short4v;
typedef __attribute__((ext_vector_type(4))) float f32x4;
typedef __attribute__((ext_vector_type(16))) float f32x16;  // 32x32 accumulator
typedef __attribute__((ext_vector_type(4))) unsigned int uint4v;
typedef __attribute__((ext_vector_type(2))) unsigned int uint2v;

// raw workgroup barrier: waits LDS ops only — global prefetches stay in flight
#define BARRIER() asm volatile("s_waitcnt lgkmcnt(0)\n\ts_barrier" ::: "memory")

__device__ inline float fast_exp2(float x) {
#if __has_builtin(__builtin_amdgcn_exp2f)
  return __builtin_amdgcn_exp2f(x);
#else
  return exp2f(x);
#endif
}

// pack 8 f32 (reg-order r0..r7 of a 32x32 D half) into one 16B granule word via
// cvt_pk(RNE) + permlane32_swap — layout verified on-silicon in R12's producer.
#define PACK8_STORE(EX0,EX1,EX2,EX3,EX4,EX5,EX6,EX7, DSTPTR)                         \
  {                                                                                  \
    unsigned pw0, pw1, pw2, pw3;                                                     \
    asm("v_cvt_pk_bf16_f32 %0, %1, %2" : "=v"(pw0) : "v"(EX0), "v"(EX1));            \
    asm("v_cvt_pk_bf16_f32 %0, %1, %2" : "=v"(pw1) : "v"(EX2), "v"(EX3));            \
    asm("v_cvt_pk_bf16_f32 %0, %1, %2" : "=v"(pw2) : "v"(EX4), "v"(EX5));            \
    asm("v_cvt_pk_bf16_f32 %0, %1, %2" : "=v"(pw3) : "v"(EX6), "v"(EX7));            \
    asm("v_permlane32_swap_b32 %0, %1" : "+v"(pw0), "+v"(pw2));                      \
    asm("v_permlane32_swap_b32 %0, %1" : "+v"(pw1), "+v"(pw3));                      \
    uint4v pu; pu.x = pw0; pu.y = pw1; pu.z = pw2; pu.w = pw3;                       \
    *(uint4v*)(DSTPTR) = pu;                                                         \
  }

// ---------------- kernel 0: W -> 32x32-granule layout ----------------
// wf[tile(10)][chunk(16)][lane(64)][8]: element = W*[o = lane&31][cin = 16c+8hi+j].
// tile 0 = Wq (x log2e), 1 = Wk, 2..9 = Wv 32-ch tiles. Serves as A-frag (q,k: row=o)
// and B-frag (v: col=o) — same granule either way.
__global__ __launch_bounds__(256) void wprep_kernel(
    const float* __restrict__ Wq, const float* __restrict__ Wk, const float* __restrict__ Wv,
    unsigned short* __restrict__ wf)
{
  const int t = threadIdx.x;
  const int g = blockIdx.x * 4 + (t >> 6);        // granule 0..159
  const int lane = t & 63, ql = lane & 31, hi = lane >> 5;
  const int tile = g >> 4, chunk = g & 15;
  const int cin = chunk * 16 + hi * 8;
  const float* src;
  float sc = 1.0f;
  if (tile == 0)      { src = Wq + (size_t)ql * CC; sc = LOG2E; }
  else if (tile == 1) { src = Wk + (size_t)ql * CC; }
  else                { src = Wv + (size_t)(32 * (tile - 2) + ql) * CC; }
  const f32x4 a = *(const f32x4*)(src + cin);
  const f32x4 b2 = *(const f32x4*)(src + cin + 4);
  unsigned w0, w1, w2, w3;
  const float f0 = a[0] * sc, f1 = a[1] * sc, f2 = a[2] * sc, f3 = a[3] * sc;
  const float f4 = b2[0] * sc, f5 = b2[1] * sc, f6 = b2[2] * sc, f7 = b2[3] * sc;
  asm("v_cvt_pk_bf16_f32 %0, %1, %2" : "=v"(w0) : "v"(f0), "v"(f1));
  asm("v_cvt_pk_bf16_f32 %0, %1, %2" : "=v"(w1) : "v"(f2), "v"(f3));
  asm("v_cvt_pk_bf16_f32 %0, %1, %2" : "=v"(w2) : "v"(f4), "v"(f5));
  asm("v_cvt_pk_bf16_f32 %0, %1, %2" : "=v"(w3) : "v"(f6), "v"(f7));
  uint4v u; u.x = w0; u.y = w1; u.z = w2; u.w = w3;
  *(uint4v*)(wf + ((size_t)g * 64 + lane) * 8) = u;
}

// ---------------- kernel 1: QKV projection, 32x32 MFMA, fragment-direct ----------------
// R13 rewrite: grid 512 = (b, 32-i tile), 512 thr = 8 waves.
// Stage: x staged straight into B-frag granules (scalar f32 loads are 128B/half-wave
// coalesced; cvt_pk conversion; ds_write_b128) — no f2bf chains, no scalar LDS reads.
// GEMM: wave w computes v-tile w (16 MFMA); waves 0/1 additionally Q/K.
// Epilogue: cvt_pk+permlane pack (R12-verified) emits qF/kF/vF in R12's exact layout.
__global__ __launch_bounds__(512, 4) void qkv_kernel(
    const float* __restrict__ x, const unsigned short* __restrict__ wf,
    const float* __restrict__ bq, const float* __restrict__ bk, const float* __restrict__ bv,
    unsigned short* __restrict__ qF, unsigned short* __restrict__ kF,
    unsigned short* __restrict__ vF)
{
  __shared__ __align__(16) unsigned short xb[16 * 64 * 8];   // 16 chunks x 1KB granules

  const int t = threadIdx.x;
  const int w = t >> 6, lane = t & 63, ql = lane & 31, hi = lane >> 5;
  const int blk = blockIdx.x;
  const int b  = (blk & 7) >> 1;                   // XCD-batch affinity
  const int it = ((blk >> 3) << 1) + (blk & 1);    // 0..127 (32-i tile)
  const int i0 = it * 32;

  // ---- stage x -> xb granules: wave w covers chunks 2w, 2w+1 ----
  #pragma unroll
  for (int e = 0; e < 2; ++e) {
    const int cc = 2 * w + e;
    const float* xs = x + ((size_t)(b * CC + cc * 16 + hi * 8)) * LL + i0 + ql;
    float f[8];
    #pragma unroll
    for (int j = 0; j < 8; ++j) f[j] = xs[(size_t)j * LL];
    unsigned w0, w1, w2, w3;
    asm("v_cvt_pk_bf16_f32 %0, %1, %2" : "=v"(w0) : "v"(f[0]), "v"(f[1]));
    asm("v_cvt_pk_bf16_f32 %0, %1, %2" : "=v"(w1) : "v"(f[2]), "v"(f[3]));
    asm("v_cvt_pk_bf16_f32 %0, %1, %2" : "=v"(w2) : "v"(f[4]), "v"(f[5]));
    asm("v_cvt_pk_bf16_f32 %0, %1, %2" : "=v"(w3) : "v"(f[6]), "v"(f[7]));
    uint4v u; u.x = w0; u.y = w1; u.z = w2; u.w = w3;
    *(uint4v*)&xb[(cc * 64 + lane) * 8] = u;
  }
  __syncthreads();

  const f32x16 z16 = {0.f,0.f,0.f,0.f,0.f,0.f,0.f,0.f,0.f,0.f,0.f,0.f,0.f,0.f,0.f,0.f};

  // ---- V tile m = w: D = x-frag(A: rows i) x Wv-frag(B: cols ch) ----
  {
    f32x16 D = z16;
    #pragma unroll
    for (int c = 0; c < 16; ++c) {
      const short8 xc = *(const short8*)&xb[(c * 64 + lane) * 8];
      const short8 wv = *(const short8*)(wf + ((size_t)((2 + w) * 16 + c) * 64 + lane) * 8);
      D = __builtin_amdgcn_mfma_f32_32x32x16_bf16(xc, wv, D, 0, 0, 0);
    }
    const float bvv = bv[32 * w + ql];   // lane = ch: one bias for all regs
    #pragma unroll
    for (int r = 0; r < 16; ++r) D[r] += bvv;
    // sub s: regs 8s..8s+7 = keys 16s..16s+15 -> vF granule (kg = 2*it+s, m = w)
    #pragma unroll
    for (int s = 0; s < 2; ++s) {
      unsigned short* dst = vF + (((size_t)(b * 256 + 2 * it + s) * 8 + w) * 64 + lane) * 8;
      PACK8_STORE(D[8*s+0], D[8*s+1], D[8*s+2], D[8*s+3],
                  D[8*s+4], D[8*s+5], D[8*s+6], D[8*s+7], dst);
    }
  }

  // ---- Q (wave 0) / K (wave 1): D = W-frag(A: rows ch) x x-frag(B: cols i) ----
  if (w < 2) {
    const float* bsrc = w ? bk : bq;
    const float bscale = w ? 1.0f : LOG2E;
    float br[16];
    #pragma unroll
    for (int r = 0; r < 16; ++r)
      br[r] = bsrc[(r & 3) + 8 * (r >> 2) + 4 * hi] * bscale;
    f32x16 D = z16;
    #pragma unroll
    for (int c = 0; c < 16; ++c) {
      const short8 xc = *(const short8*)&xb[(c * 64 + lane) * 8];
      const short8 wa = *(const short8*)(wf + ((size_t)(w * 16 + c) * 64 + lane) * 8);
      D = __builtin_amdgcn_mfma_f32_32x32x16_bf16(wa, xc, D, 0, 0, 0);
    }
    #pragma unroll
    for (int r = 0; r < 16; ++r) D[r] += br[r];
    unsigned short* basef = w ? kF : qF;
    // sub s: regs 8s..8s+7 = ch 16s..16s+15 -> granule (tile it, chunk s)
    #pragma unroll
    for (int s = 0; s < 2; ++s) {
      unsigned short* dst = basef + (((size_t)(b * 128 + it) * 2 + s) * 64 + lane) * 8;
      PACK8_STORE(D[8*s+0], D[8*s+1], D[8*s+2], D[8*s+3],
                  D[8*s+4], D[8*s+5], D[8*s+6], D[8*s+7], dst);
    }
  }
}

// ---------------- kernel 2: flash attention, 32x32 MFMA, producer/consumer ----------------
// (unchanged from R12 — control for this round)
__global__ __launch_bounds__(768, 3) void attn_kernel(
    const unsigned short* __restrict__ qF, const unsigned short* __restrict__ kF,
    const unsigned short* __restrict__ vF, const float* __restrict__ x,
    const float* __restrict__ gamma_p, float* __restrict__ out)
{
  __shared__ __align__(16) unsigned short P[2 * 8 * 2 * 2 * 512];  // 64 KB ring (2 bufs)
  __shared__ float l_lds[8][2][64];                                // [pw][qt][lane] 4 KB

  const int t = threadIdx.x;
  const int w = t >> 6, lane = t & 63, ql = lane & 31, hi = lane >> 5;
  const int blk = blockIdx.x;
  const int b  = (blk & 7) >> 1;                          // matches qkv affinity
  const int it = ((blk >> 3) << 1) + (blk & 1);           // 0..63
  const int i0 = it * 64;

  if (w < 8) {
    // ================= producer: key-tile kk = pw of each window =================
    const int pw = w;
    short8 qB[2][2];                       // [qt][chunk]
    #pragma unroll
    for (int qt = 0; qt < 2; ++qt)
      #pragma unroll
      for (int c = 0; c < 2; ++c)
        qB[qt][c] = *(const short8*)(qF +
            (((size_t)(b * 128 + it * 2 + qt) * 2 + c) * 64 + lane) * 8);
    short8 kA[2];                          // [chunk], tile ss*8+pw
    #pragma unroll
    for (int c = 0; c < 2; ++c)
      kA[c] = *(const short8*)(kF + (((size_t)(b * 128 + pw) * 2 + c) * 64 + lane) * 8);
    float l_r[2] = {0.f, 0.f};
    const f32x16 z16 = {0.f,0.f,0.f,0.f,0.f,0.f,0.f,0.f,0.f,0.f,0.f,0.f,0.f,0.f,0.f,0.f};

    auto produce = [&](int ss, int buf) {
      f32x16 S[2];
      __builtin_amdgcn_s_setprio(1);
      #pragma unroll
      for (int qt = 0; qt < 2; ++qt)
        S[qt] = __builtin_amdgcn_mfma_f32_32x32x16_bf16(kA[0], qB[qt][0], z16, 0, 0, 0);
      #pragma unroll
      for (int qt = 0; qt < 2; ++qt)
        S[qt] = __builtin_amdgcn_mfma_f32_32x32x16_bf16(kA[1], qB[qt][1], S[qt], 0, 0, 0);
      __builtin_amdgcn_s_setprio(0);
      // prefetch next window's kA (global; stays in flight across barrier)
      const int ntile = ((ss + 1) & 15) * 8 + pw;
      #pragma unroll
      for (int c = 0; c < 2; ++c)
        kA[c] = *(const short8*)(kF + (((size_t)(b * 128 + ntile) * 2 + c) * 64 + lane) * 8);
      // exp + pack: D row = (r&3)+8*(r>>2)+4*hi (key), col = q = l&31
      #pragma unroll
      for (int qt = 0; qt < 2; ++qt) {
        float ex[16];
        #pragma unroll
        for (int r = 0; r < 16; ++r) ex[r] = fast_exp2(S[qt][r]);
        l_r[qt] += ((((ex[0] + ex[1]) + (ex[2] + ex[3])) + ((ex[4] + ex[5]) + (ex[6] + ex[7])))
                 + (((ex[8] + ex[9]) + (ex[10] + ex[11])) + ((ex[12] + ex[13]) + (ex[14] + ex[15]))));
        #pragma unroll
        for (int c = 0; c < 2; ++c) {
          unsigned short* dst = &P[(((buf * 8 + pw) * 2 + qt) * 2 + c) * 512 + hi * 256 + ql * 8];
          PACK8_STORE(ex[8*c+0], ex[8*c+1], ex[8*c+2], ex[8*c+3],
                      ex[8*c+4], ex[8*c+5], ex[8*c+6], ex[8*c+7], dst);
        }
      }
    };

    produce(0, 0);
    __syncthreads();   // P(0) ready
    for (int i = 0; i < 16; ++i) {
      if (i < 15) produce(i + 1, (i + 1) & 1);
      BARRIER();
    }
    l_lds[pw][0][lane] = l_r[0];
    l_lds[pw][1][lane] = l_r[1];
    BARRIER();
  } else {
    // ================= consumer: ch 64*mq..+63 over ALL keys =================
    const int mq = w - 8;
    const unsigned short* vroot = vF + (size_t)b * (256 * 8 * 512) + lane * 8;
    f32x16 O[2][2];                       // [mi][qt]
    #pragma unroll
    for (int mi = 0; mi < 2; ++mi)
      #pragma unroll
      for (int qt = 0; qt < 2; ++qt) {
        const f32x16 z16 = {0.f,0.f,0.f,0.f,0.f,0.f,0.f,0.f,0.f,0.f,0.f,0.f,0.f,0.f,0.f,0.f};
        O[mi][qt] = z16;
      }
    short8 vA[4][2];                      // 4-slot ring [g&3][mi], ~250 cyc slack
    #pragma unroll
    for (int s = 0; s < 4; ++s)
      #pragma unroll
      for (int mi = 0; mi < 2; ++mi)
        vA[s][mi] = *(const short8*)(vroot + ((size_t)(s * 8 + 2 * mq + mi)) * 512);
    __syncthreads();   // P(0) ready

    short8 pb[3][2];                      // 3-slot ring [s%3][qt]
    for (int i = 0; i < 16; ++i) {
      const int buf = i & 1;
      // preload steps 0,1 (kk=0, c=0/1)
      #pragma unroll
      for (int s = 0; s < 2; ++s)
        #pragma unroll
        for (int qt = 0; qt < 2; ++qt)
          pb[s][qt] = *(const short8*)(&P[((((buf * 8 + 0) * 2 + qt) * 2 + s) * 512)
                                          + hi * 256 + ql * 8]);
      #pragma unroll
      for (int s = 0; s < 16; ++s) {      // step s: kk = s>>1, c = s&1
        if (s < 14) {                     // prefetch pb 2 steps ahead
          const int ns = s + 2, kk = ns >> 1, c = ns & 1;
          #pragma unroll
          for (int qt = 0; qt < 2; ++qt)
            pb[ns % 3][qt] = *(const short8*)(&P[((((buf * 8 + kk) * 2 + qt) * 2 + c) * 512)
                                                 + hi * 256 + ql * 8]);
        }
        __builtin_amdgcn_s_setprio(1);
        #pragma unroll
        for (int mi = 0; mi < 2; ++mi)
          #pragma unroll
          for (int qt = 0; qt < 2; ++qt)
            O[mi][qt] = __builtin_amdgcn_mfma_f32_32x32x16_bf16(vA[s & 3][mi], pb[s % 3][qt],
                                                                O[mi][qt], 0, 0, 0);
        __builtin_amdgcn_s_setprio(0);
        // refill vA slot s&3 with key-group 4 steps ahead (wraps across windows)
        const int kg = (i * 16 + s + 4) & 255;
        #pragma unroll
        for (int mi = 0; mi < 2; ++mi)
          vA[s & 3][mi] = *(const short8*)(vroot + ((size_t)(kg * 8 + 2 * mq + mi)) * 512);
      }
      BARRIER();
    }
    BARRIER();   // l_lds visible

    // ---- epilogue: no cross-wave O combine; normalize + residual ----
    const float gam = gamma_p[0];
    float inv_l[2];
    #pragma unroll
    for (int qt = 0; qt < 2; ++qt) {
      float s = 0.f;
      #pragma unroll
      for (int pw = 0; pw < 8; ++pw)
        s += l_lds[pw][qt][ql] + l_lds[pw][qt][ql + 32];
      inv_l[qt] = 1.0f / s;
    }
    #pragma unroll
    for (int mi = 0; mi < 2; ++mi)
      #pragma unroll
      for (int qt = 0; qt < 2; ++qt)
        #pragma unroll
        for (int r = 0; r < 16; ++r) {
          const int ch = 64 * mq + 32 * mi + (r & 3) + 8 * (r >> 2) + 4 * hi;
          const int ii = i0 + 32 * qt + ql;
          const size_t idx = ((size_t)b * CC + ch) * LL + ii;
          out[idx] = gam * O[mi][qt][r] * inv_l[qt] + x[idx];
        }
  }
}

extern "C" void kernel_launch(void* const* d_in, const int* in_sizes, int n_in,
                              void* d_out, int out_size, void* d_ws, size_t ws_size,
                              hipStream_t stream) {
  const float* x     = (const float*)d_in[0];
  const float* Wq    = (const float*)d_in[1];
  const float* bq    = (const float*)d_in[2];
  const float* Wk    = (const float*)d_in[3];
  const float* bk    = (const float*)d_in[4];
  const float* Wv    = (const float*)d_in[5];
  const float* bv    = (const float*)d_in[6];
  const float* gamma = (const float*)d_in[7];
  float* out = (float*)d_out;

  // ws: qF (1MB) | kF (1MB) | vF (8MB) — all 32x32-fragment-linear bf16
  unsigned short* qF = (unsigned short*)d_ws;
  unsigned short* kF = qF + (size_t)BB * LL * DD;
  unsigned short* vF = kF + (size_t)BB * LL * DD;
  // wf (160KB granules) lives in d_out; consumed by qkv, then attn overwrites d_out
  unsigned short* wf = (unsigned short*)d_out;

  wprep_kernel<<<40, 256, 0, stream>>>(Wq, Wk, Wv, wf);
  qkv_kernel<<<512, 512, 0, stream>>>(x, wf, bq, bk, bv, qF, kF, vF);
  attn_kernel<<<256, 768, 0, stream>>>(qF, kF, vF, x, gamma, out);
}

// Round 8
// 129.555 us; speedup vs baseline: 1.0314x; 1.0022x over previous
//
#include <hip/hip_runtime.h>
#include <math.h>

#define BB 4
#define CC 256
#define LL 4096
#define DD 32   // q/k channels
#define LOG2E 1.44269504088896f

typedef __attribute__((ext_vector_type(8))) short short8;   // 8 bf16 (4 VGPRs)
typedef __attribute__((ext_vector_type(4))) short short4v;
typedef __attribute__((ext_vector_type(4))) float f32x4;
typedef __attribute__((ext_vector_type(16))) float f32x16;  // 32x32 accumulator
typedef __attribute__((ext_vector_type(4))) unsigned int uint4v;
typedef __attribute__((ext_vector_type(2))) unsigned int uint2v;

// raw workgroup barrier: waits LDS ops only — global prefetches stay in flight
#define BARRIER() asm volatile("s_waitcnt lgkmcnt(0)\n\ts_barrier" ::: "memory")

__device__ inline float fast_exp2(float x) {
#if __has_builtin(__builtin_amdgcn_exp2f)
  return __builtin_amdgcn_exp2f(x);
#else
  return exp2f(x);
#endif
}

// pack 8 f32 (reg-order r0..r7 of a 32x32 D half) into one 16B granule word via
// cvt_pk(RNE) + permlane32_swap — layout verified on-silicon in R12's producer.
#define PACK8_STORE(EX0,EX1,EX2,EX3,EX4,EX5,EX6,EX7, DSTPTR)                         \
  {                                                                                  \
    unsigned pw0, pw1, pw2, pw3;                                                     \
    asm("v_cvt_pk_bf16_f32 %0, %1, %2" : "=v"(pw0) : "v"(EX0), "v"(EX1));            \
    asm("v_cvt_pk_bf16_f32 %0, %1, %2" : "=v"(pw1) : "v"(EX2), "v"(EX3));            \
    asm("v_cvt_pk_bf16_f32 %0, %1, %2" : "=v"(pw2) : "v"(EX4), "v"(EX5));            \
    asm("v_cvt_pk_bf16_f32 %0, %1, %2" : "=v"(pw3) : "v"(EX6), "v"(EX7));            \
    asm("v_permlane32_swap_b32 %0, %1" : "+v"(pw0), "+v"(pw2));                      \
    asm("v_permlane32_swap_b32 %0, %1" : "+v"(pw1), "+v"(pw3));                      \
    uint4v pu; pu.x = pw0; pu.y = pw1; pu.z = pw2; pu.w = pw3;                       \
    *(uint4v*)(DSTPTR) = pu;                                                         \
  }

// ---------------- kernel 0: W -> 32x32-granule layout ----------------
// wf[tile(10)][chunk(16)][lane(64)][8]: element = W*[o = lane&31][cin = 16c+8hi+j].
// tile 0 = Wq (x log2e), 1 = Wk, 2..9 = Wv 32-ch tiles. Serves as A-frag (q,k: row=o)
// and B-frag (v: col=o) — same granule either way.
__global__ __launch_bounds__(256) void wprep_kernel(
    const float* __restrict__ Wq, const float* __restrict__ Wk, const float* __restrict__ Wv,
    unsigned short* __restrict__ wf)
{
  const int t = threadIdx.x;
  const int g = blockIdx.x * 4 + (t >> 6);        // granule 0..159
  const int lane = t & 63, ql = lane & 31, hi = lane >> 5;
  const int tile = g >> 4, chunk = g & 15;
  const int cin = chunk * 16 + hi * 8;
  const float* src;
  float sc = 1.0f;
  if (tile == 0)      { src = Wq + (size_t)ql * CC; sc = LOG2E; }
  else if (tile == 1) { src = Wk + (size_t)ql * CC; }
  else                { src = Wv + (size_t)(32 * (tile - 2) + ql) * CC; }
  const f32x4 a = *(const f32x4*)(src + cin);
  const f32x4 b2 = *(const f32x4*)(src + cin + 4);
  unsigned w0, w1, w2, w3;
  const float f0 = a[0] * sc, f1 = a[1] * sc, f2 = a[2] * sc, f3 = a[3] * sc;
  const float f4 = b2[0] * sc, f5 = b2[1] * sc, f6 = b2[2] * sc, f7 = b2[3] * sc;
  asm("v_cvt_pk_bf16_f32 %0, %1, %2" : "=v"(w0) : "v"(f0), "v"(f1));
  asm("v_cvt_pk_bf16_f32 %0, %1, %2" : "=v"(w1) : "v"(f2), "v"(f3));
  asm("v_cvt_pk_bf16_f32 %0, %1, %2" : "=v"(w2) : "v"(f4), "v"(f5));
  asm("v_cvt_pk_bf16_f32 %0, %1, %2" : "=v"(w3) : "v"(f6), "v"(f7));
  uint4v u; u.x = w0; u.y = w1; u.z = w2; u.w = w3;
  *(uint4v*)(wf + ((size_t)g * 64 + lane) * 8) = u;
}

// ---------------- kernel 1: QKV projection, 32x32 MFMA, fragment-direct ----------------
// (unchanged from R13)
__global__ __launch_bounds__(512, 4) void qkv_kernel(
    const float* __restrict__ x, const unsigned short* __restrict__ wf,
    const float* __restrict__ bq, const float* __restrict__ bk, const float* __restrict__ bv,
    unsigned short* __restrict__ qF, unsigned short* __restrict__ kF,
    unsigned short* __restrict__ vF)
{
  __shared__ __align__(16) unsigned short xb[16 * 64 * 8];   // 16 chunks x 1KB granules

  const int t = threadIdx.x;
  const int w = t >> 6, lane = t & 63, ql = lane & 31, hi = lane >> 5;
  const int blk = blockIdx.x;
  const int b  = (blk & 7) >> 1;                   // XCD-batch affinity
  const int it = ((blk >> 3) << 1) + (blk & 1);    // 0..127 (32-i tile)
  const int i0 = it * 32;

  // ---- stage x -> xb granules: wave w covers chunks 2w, 2w+1 ----
  #pragma unroll
  for (int e = 0; e < 2; ++e) {
    const int cc = 2 * w + e;
    const float* xs = x + ((size_t)(b * CC + cc * 16 + hi * 8)) * LL + i0 + ql;
    float f[8];
    #pragma unroll
    for (int j = 0; j < 8; ++j) f[j] = xs[(size_t)j * LL];
    unsigned w0, w1, w2, w3;
    asm("v_cvt_pk_bf16_f32 %0, %1, %2" : "=v"(w0) : "v"(f[0]), "v"(f[1]));
    asm("v_cvt_pk_bf16_f32 %0, %1, %2" : "=v"(w1) : "v"(f[2]), "v"(f[3]));
    asm("v_cvt_pk_bf16_f32 %0, %1, %2" : "=v"(w2) : "v"(f[4]), "v"(f[5]));
    asm("v_cvt_pk_bf16_f32 %0, %1, %2" : "=v"(w3) : "v"(f[6]), "v"(f[7]));
    uint4v u; u.x = w0; u.y = w1; u.z = w2; u.w = w3;
    *(uint4v*)&xb[(cc * 64 + lane) * 8] = u;
  }
  __syncthreads();

  const f32x16 z16 = {0.f,0.f,0.f,0.f,0.f,0.f,0.f,0.f,0.f,0.f,0.f,0.f,0.f,0.f,0.f,0.f};

  // ---- V tile m = w: D = x-frag(A: rows i) x Wv-frag(B: cols ch) ----
  {
    f32x16 D = z16;
    #pragma unroll
    for (int c = 0; c < 16; ++c) {
      const short8 xc = *(const short8*)&xb[(c * 64 + lane) * 8];
      const short8 wv = *(const short8*)(wf + ((size_t)((2 + w) * 16 + c) * 64 + lane) * 8);
      D = __builtin_amdgcn_mfma_f32_32x32x16_bf16(xc, wv, D, 0, 0, 0);
    }
    const float bvv = bv[32 * w + ql];   // lane = ch: one bias for all regs
    #pragma unroll
    for (int r = 0; r < 16; ++r) D[r] += bvv;
    // sub s: regs 8s..8s+7 = keys 16s..16s+15 -> vF granule (kg = 2*it+s, m = w)
    #pragma unroll
    for (int s = 0; s < 2; ++s) {
      unsigned short* dst = vF + (((size_t)(b * 256 + 2 * it + s) * 8 + w) * 64 + lane) * 8;
      PACK8_STORE(D[8*s+0], D[8*s+1], D[8*s+2], D[8*s+3],
                  D[8*s+4], D[8*s+5], D[8*s+6], D[8*s+7], dst);
    }
  }

  // ---- Q (wave 0) / K (wave 1): D = W-frag(A: rows ch) x x-frag(B: cols i) ----
  if (w < 2) {
    const float* bsrc = w ? bk : bq;
    const float bscale = w ? 1.0f : LOG2E;
    float br[16];
    #pragma unroll
    for (int r = 0; r < 16; ++r)
      br[r] = bsrc[(r & 3) + 8 * (r >> 2) + 4 * hi] * bscale;
    f32x16 D = z16;
    #pragma unroll
    for (int c = 0; c < 16; ++c) {
      const short8 xc = *(const short8*)&xb[(c * 64 + lane) * 8];
      const short8 wa = *(const short8*)(wf + ((size_t)(w * 16 + c) * 64 + lane) * 8);
      D = __builtin_amdgcn_mfma_f32_32x32x16_bf16(wa, xc, D, 0, 0, 0);
    }
    #pragma unroll
    for (int r = 0; r < 16; ++r) D[r] += br[r];
    unsigned short* basef = w ? kF : qF;
    // sub s: regs 8s..8s+7 = ch 16s..16s+15 -> granule (tile it, chunk s)
    #pragma unroll
    for (int s = 0; s < 2; ++s) {
      unsigned short* dst = basef + (((size_t)(b * 128 + it) * 2 + s) * 64 + lane) * 8;
      PACK8_STORE(D[8*s+0], D[8*s+1], D[8*s+2], D[8*s+3],
                  D[8*s+4], D[8*s+5], D[8*s+6], D[8*s+7], dst);
    }
  }
}

// ---------------- kernel 2: flash attention, 32x32 MFMA, producer/consumer ----------------
// R14: single-variable probe of the L2-latency theory — consumer vA ring deepened
// 4 -> 8 slots (refill issued 8 steps ≈ 512 issue-cyc before consumption, vs ~250).
// Everything else identical to R12/R13.
__global__ __launch_bounds__(768, 3) void attn_kernel(
    const unsigned short* __restrict__ qF, const unsigned short* __restrict__ kF,
    const unsigned short* __restrict__ vF, const float* __restrict__ x,
    const float* __restrict__ gamma_p, float* __restrict__ out)
{
  __shared__ __align__(16) unsigned short P[2 * 8 * 2 * 2 * 512];  // 64 KB ring (2 bufs)
  __shared__ float l_lds[8][2][64];                                // [pw][qt][lane] 4 KB

  const int t = threadIdx.x;
  const int w = t >> 6, lane = t & 63, ql = lane & 31, hi = lane >> 5;
  const int blk = blockIdx.x;
  const int b  = (blk & 7) >> 1;                          // matches qkv affinity
  const int it = ((blk >> 3) << 1) + (blk & 1);           // 0..63
  const int i0 = it * 64;

  if (w < 8) {
    // ================= producer: key-tile kk = pw of each window =================
    const int pw = w;
    short8 qB[2][2];                       // [qt][chunk]
    #pragma unroll
    for (int qt = 0; qt < 2; ++qt)
      #pragma unroll
      for (int c = 0; c < 2; ++c)
        qB[qt][c] = *(const short8*)(qF +
            (((size_t)(b * 128 + it * 2 + qt) * 2 + c) * 64 + lane) * 8);
    short8 kA[2];                          // [chunk], tile ss*8+pw
    #pragma unroll
    for (int c = 0; c < 2; ++c)
      kA[c] = *(const short8*)(kF + (((size_t)(b * 128 + pw) * 2 + c) * 64 + lane) * 8);
    float l_r[2] = {0.f, 0.f};
    const f32x16 z16 = {0.f,0.f,0.f,0.f,0.f,0.f,0.f,0.f,0.f,0.f,0.f,0.f,0.f,0.f,0.f,0.f};

    auto produce = [&](int ss, int buf) {
      f32x16 S[2];
      __builtin_amdgcn_s_setprio(1);
      #pragma unroll
      for (int qt = 0; qt < 2; ++qt)
        S[qt] = __builtin_amdgcn_mfma_f32_32x32x16_bf16(kA[0], qB[qt][0], z16, 0, 0, 0);
      #pragma unroll
      for (int qt = 0; qt < 2; ++qt)
        S[qt] = __builtin_amdgcn_mfma_f32_32x32x16_bf16(kA[1], qB[qt][1], S[qt], 0, 0, 0);
      __builtin_amdgcn_s_setprio(0);
      // prefetch next window's kA (global; stays in flight across barrier)
      const int ntile = ((ss + 1) & 15) * 8 + pw;
      #pragma unroll
      for (int c = 0; c < 2; ++c)
        kA[c] = *(const short8*)(kF + (((size_t)(b * 128 + ntile) * 2 + c) * 64 + lane) * 8);
      // exp + pack: D row = (r&3)+8*(r>>2)+4*hi (key), col = q = l&31
      #pragma unroll
      for (int qt = 0; qt < 2; ++qt) {
        float ex[16];
        #pragma unroll
        for (int r = 0; r < 16; ++r) ex[r] = fast_exp2(S[qt][r]);
        l_r[qt] += ((((ex[0] + ex[1]) + (ex[2] + ex[3])) + ((ex[4] + ex[5]) + (ex[6] + ex[7])))
                 + (((ex[8] + ex[9]) + (ex[10] + ex[11])) + ((ex[12] + ex[13]) + (ex[14] + ex[15]))));
        #pragma unroll
        for (int c = 0; c < 2; ++c) {
          unsigned short* dst = &P[(((buf * 8 + pw) * 2 + qt) * 2 + c) * 512 + hi * 256 + ql * 8];
          PACK8_STORE(ex[8*c+0], ex[8*c+1], ex[8*c+2], ex[8*c+3],
                      ex[8*c+4], ex[8*c+5], ex[8*c+6], ex[8*c+7], dst);
        }
      }
    };

    produce(0, 0);
    __syncthreads();   // P(0) ready
    for (int i = 0; i < 16; ++i) {
      if (i < 15) produce(i + 1, (i + 1) & 1);
      BARRIER();
    }
    l_lds[pw][0][lane] = l_r[0];
    l_lds[pw][1][lane] = l_r[1];
    BARRIER();
  } else {
    // ================= consumer: ch 64*mq..+63 over ALL keys =================
    const int mq = w - 8;
    const unsigned short* vroot = vF + (size_t)b * (256 * 8 * 512) + lane * 8;
    f32x16 O[2][2];                       // [mi][qt]
    #pragma unroll
    for (int mi = 0; mi < 2; ++mi)
      #pragma unroll
      for (int qt = 0; qt < 2; ++qt) {
        const f32x16 z16 = {0.f,0.f,0.f,0.f,0.f,0.f,0.f,0.f,0.f,0.f,0.f,0.f,0.f,0.f,0.f,0.f};
        O[mi][qt] = z16;
      }
    short8 vA[8][2];                      // 8-slot ring [g&7][mi]: ~512 cyc lookahead
    #pragma unroll
    for (int s = 0; s < 8; ++s)
      #pragma unroll
      for (int mi = 0; mi < 2; ++mi)
        vA[s][mi] = *(const short8*)(vroot + ((size_t)(s * 8 + 2 * mq + mi)) * 512);
    __syncthreads();   // P(0) ready

    short8 pb[3][2];                      // 3-slot ring [s%3][qt]
    for (int i = 0; i < 16; ++i) {
      const int buf = i & 1;
      // preload steps 0,1 (kk=0, c=0/1)
      #pragma unroll
      for (int s = 0; s < 2; ++s)
        #pragma unroll
        for (int qt = 0; qt < 2; ++qt)
          pb[s][qt] = *(const short8*)(&P[((((buf * 8 + 0) * 2 + qt) * 2 + s) * 512)
                                          + hi * 256 + ql * 8]);
      #pragma unroll
      for (int s = 0; s < 16; ++s) {      // step s: kk = s>>1, c = s&1
        if (s < 14) {                     // prefetch pb 2 steps ahead
          const int ns = s + 2, kk = ns >> 1, c = ns & 1;
          #pragma unroll
          for (int qt = 0; qt < 2; ++qt)
            pb[ns % 3][qt] = *(const short8*)(&P[((((buf * 8 + kk) * 2 + qt) * 2 + c) * 512)
                                                 + hi * 256 + ql * 8]);
        }
        __builtin_amdgcn_s_setprio(1);
        #pragma unroll
        for (int mi = 0; mi < 2; ++mi)
          #pragma unroll
          for (int qt = 0; qt < 2; ++qt)
            O[mi][qt] = __builtin_amdgcn_mfma_f32_32x32x16_bf16(vA[s & 7][mi], pb[s % 3][qt],
                                                                O[mi][qt], 0, 0, 0);
        __builtin_amdgcn_s_setprio(0);
        // refill vA slot s&7 with key-group 8 steps ahead (wraps across windows)
        const int kg = (i * 16 + s + 8) & 255;
        #pragma unroll
        for (int mi = 0; mi < 2; ++mi)
          vA[s & 7][mi] = *(const short8*)(vroot + ((size_t)(kg * 8 + 2 * mq + mi)) * 512);
      }
      BARRIER();
    }
    BARRIER();   // l_lds visible

    // ---- epilogue: no cross-wave O combine; normalize + residual ----
    const float gam = gamma_p[0];
    float inv_l[2];
    #pragma unroll
    for (int qt = 0; qt < 2; ++qt) {
      float s = 0.f;
      #pragma unroll
      for (int pw = 0; pw < 8; ++pw)
        s += l_lds[pw][qt][ql] + l_lds[pw][qt][ql + 32];
      inv_l[qt] = 1.0f / s;
    }
    #pragma unroll
    for (int mi = 0; mi < 2; ++mi)
      #pragma unroll
      for (int qt = 0; qt < 2; ++qt)
        #pragma unroll
        for (int r = 0; r < 16; ++r) {
          const int ch = 64 * mq + 32 * mi + (r & 3) + 8 * (r >> 2) + 4 * hi;
          const int ii = i0 + 32 * qt + ql;
          const size_t idx = ((size_t)b * CC + ch) * LL + ii;
          out[idx] = gam * O[mi][qt][r] * inv_l[qt] + x[idx];
        }
  }
}

extern "C" void kernel_launch(void* const* d_in, const int* in_sizes, int n_in,
                              void* d_out, int out_size, void* d_ws, size_t ws_size,
                              hipStream_t stream) {
  const float* x     = (const float*)d_in[0];
  const float* Wq    = (const float*)d_in[1];
  const float* bq    = (const float*)d_in[2];
  const float* Wk    = (const float*)d_in[3];
  const float* bk    = (const float*)d_in[4];
  const float* Wv    = (const float*)d_in[5];
  const float* bv    = (const float*)d_in[6];
  const float* gamma = (const float*)d_in[7];
  float* out = (float*)d_out;

  // ws: qF (1MB) | kF (1MB) | vF (8MB) — all 32x32-fragment-linear bf16
  unsigned short* qF = (unsigned short*)d_ws;
  unsigned short* kF = qF + (size_t)BB * LL * DD;
  unsigned short* vF = kF + (size_t)BB * LL * DD;
  // wf (160KB granules) lives in d_out; consumed by qkv, then attn overwrites d_out
  unsigned short* wf = (unsigned short*)d_out;

  wprep_kernel<<<40, 256, 0, stream>>>(Wq, Wk, Wv, wf);
  qkv_kernel<<<512, 512, 0, stream>>>(x, wf, bq, bk, bv, qF, kF, vF);
  attn_kernel<<<256, 768, 0, stream>>>(qF, kF, vF, x, gamma, out);
}